// Round 16
// baseline (10713.420 us; speedup 1.0000x reference)
//
#include <hip/hip_runtime.h>

constexpr int F_ = 36;
constexpr int H_ = 512;
constexpr int T_ = 1500;
constexpr int C_ = 64;
constexpr int NWG = 256;
constexpr int BLK = 512;
constexpr int NW = 8;
constexpr int GW = 64;             // WGs per group
constexpr int GB = 16;             // batch elements per group
constexpr int GRING = GB * H_;     // 8192 u32 per ring buffer
constexpr int FLGSTRIDE = 32;      // one flag per 128B line
constexpr unsigned FLGN_U32 = NWG * FLGSTRIDE;   // 8192 u32 = 32KB

#define SCOPE_AGENT __HIP_MEMORY_SCOPE_AGENT

typedef __attribute__((ext_vector_type(8))) short bf16x8;
typedef __attribute__((ext_vector_type(4))) float f32x4;
typedef __attribute__((ext_vector_type(4))) unsigned u32x4;

// ---- cross-XCD primitives (R5/R6/R11/R15-proven): sc0sc1 write-through + LLC loads ----
__device__ __forceinline__ void astore_u32(unsigned* p, unsigned v) {
    __hip_atomic_store(p, v, __ATOMIC_RELAXED, SCOPE_AGENT);
}
__device__ __forceinline__ uint4 llc_load4(const unsigned* p) {
    uint4 r;
    asm volatile("global_load_dwordx4 %0, %1, off sc0 sc1" : "=v"(r) : "v"(p));
    return r;
}
__device__ __forceinline__ unsigned llc_load1(const unsigned* p) {
    unsigned r;
    asm volatile("global_load_dword %0, %1, off sc0 sc1" : "=v"(r) : "v"(p));
    return r;
}
// plain cached load, position-pinned (immutable x prefetch)
__device__ __forceinline__ float4 cload4(const float* p) {
    float4 r;
    asm volatile("global_load_dwordx4 %0, %1, off" : "=v"(r) : "v"(p));
    return r;
}
__device__ __forceinline__ void gstore4(unsigned* p, u32x4 v) {
    asm volatile("global_store_dwordx4 %0, %1, off sc0 sc1" :: "v"(p), "v"(v) : "memory");
}
// rule #18: sched_barrier(0) after inline-asm waitcnt
__device__ __forceinline__ void vm_wait0() { asm volatile("s_waitcnt vmcnt(0)" ::: "memory"); __builtin_amdgcn_sched_barrier(0); }
__device__ __forceinline__ void vm_wait1() { asm volatile("s_waitcnt vmcnt(1)" ::: "memory"); __builtin_amdgcn_sched_barrier(0); }
__device__ __forceinline__ void vm_wait4() { asm volatile("s_waitcnt vmcnt(4)" ::: "memory"); __builtin_amdgcn_sched_barrier(0); }

__device__ __forceinline__ float sigm(float x) { return 1.0f / (1.0f + __expf(-x)); }
__device__ __forceinline__ float tanhf_(float x) { return 1.0f - 2.0f / (__expf(2.0f * x) + 1.0f); }

// ---- bf16 hi/lo split machinery (R6-proven) ----
__device__ __forceinline__ unsigned bf16rne(float f) {
    unsigned u = __float_as_uint(f);
    return (u + 0x7FFFu + ((u >> 16) & 1u)) >> 16;
}
__device__ __forceinline__ unsigned packhl(float h) {
    unsigned hi = bf16rne(h);
    float lo = h - __uint_as_float(hi << 16);
    return hi | (bf16rne(lo) << 16);
}

struct Frag2 { bf16x8 hi, lo; };

__device__ __forceinline__ Frag2 split8(const float v[8]) {
    union { unsigned u[4]; bf16x8 x; } hi, lo;
    #pragma unroll
    for (int j = 0; j < 4; ++j) {
        unsigned a = bf16rne(v[2*j]), b = bf16rne(v[2*j+1]);
        float ra = v[2*j]   - __uint_as_float(a << 16);
        float rb = v[2*j+1] - __uint_as_float(b << 16);
        hi.u[j] = a | (b << 16);
        lo.u[j] = bf16rne(ra) | (bf16rne(rb) << 16);
    }
    return { hi.x, lo.x };
}
__device__ __forceinline__ Frag2 fromPacked(const uint4& q0, const uint4& q1) {
    unsigned p[8] = { q0.x, q0.y, q0.z, q0.w, q1.x, q1.y, q1.z, q1.w };
    union { unsigned u[4]; bf16x8 x; } hi, lo;
    #pragma unroll
    for (int j = 0; j < 4; ++j) {
        hi.u[j] = (p[2*j] & 0xFFFFu) | (p[2*j+1] << 16);
        lo.u[j] = (p[2*j] >> 16) | (p[2*j+1] & 0xFFFF0000u);
    }
    return { hi.x, lo.x };
}
__device__ __forceinline__ f32x4 mfma3(const Frag2& a, const Frag2& b, f32x4 c) {
    c = __builtin_amdgcn_mfma_f32_16x16x32_bf16(a.hi, b.hi, c, 0, 0, 0);
    c = __builtin_amdgcn_mfma_f32_16x16x32_bf16(a.hi, b.lo, c, 0, 0, 0);
    c = __builtin_amdgcn_mfma_f32_16x16x32_bf16(a.lo, b.hi, c, 0, 0, 0);
    return c;
}
__device__ Frag2 gatherA(const float* W, int rstride, int grow, int colbase, int ncols, int kq) {
    float v[8];
    #pragma unroll
    for (int e = 0; e < 8; ++e) {
        int col = colbase + kq * 8 + e;
        v[e] = (col < ncols) ? W[(size_t)grow * rstride + col] : 0.0f;
    }
    return split8(v);
}

__global__ void __launch_bounds__(BLK, 2) lstm_all(
    const float* __restrict__ x,
    const float* __restrict__ Wih0, const float* __restrict__ Whh0,
    const float* __restrict__ bih0, const float* __restrict__ bhh0,
    const float* __restrict__ Wih1, const float* __restrict__ Whh1,
    const float* __restrict__ bih1, const float* __restrict__ bhh1,
    const float* __restrict__ Wout, const float* __restrict__ bout,
    float* __restrict__ out, unsigned* __restrict__ wsu)
{
    const int w = blockIdx.x, tid = threadIdx.x;
    const int v = tid >> 6, lane = tid & 63;
    const int bl = lane & 15;        // B-frag col = group-local batch / A-row within tile
    const int kq = lane >> 4;        // k-quarter within frag
    const int g = w >> 6, lw = w & 63;   // group, WG-in-group

    __shared__ float parts[NW][2][2][4][65];   // [wave][layer][row-tile][reg][lane(+pad)]
    __shared__ float cs[2][8][GB];             // cell state [layer][unit][b]
    __shared__ float bias[2][4][8];            // [layer][gate][unit]
    __shared__ unsigned hstage[2][8][GB];      // packed h staging [layer][unit][b]

    unsigned* flags = wsu;                     // flag[w] at w*FLGSTRIDE (line-padded)
    unsigned* greg = wsu + FLGN_U32 + (size_t)g * 4 * GRING;   // group ring region
    unsigned* h1r[2] = { greg, greg + GRING };
    unsigned* h2r[2] = { greg + 2 * GRING, greg + 3 * GRING };

    // ---- init: zero this group's rings (exactly one u32 per thread), cs, bias ----
    astore_u32(greg + lw * BLK + tid, 0u);     // 64 WGs x 512 = 32768 = 4*GRING
    if (tid < 256) ((float*)cs)[tid] = 0.0f;   // 2*8*16 = 256
    if (tid < 64) {
        int layer = tid >> 5, gate = (tid >> 3) & 3, u = tid & 7;
        int grow = gate * H_ + lw * 8 + u;
        bias[layer][gate][u] = layer ? (bih1[grow] + bhh1[grow]) : (bih0[grow] + bhh0[grow]);
    }

    // ---- A-fragments in VGPRs. Row mapping per layer: r = gate*8 + u (0..31),
    //      row-tile rt = r>>4; within tile, lane bl: gate = rt*2+(bl>>3), u = bl&7.
    Frag2 A10[2][2], A11[2][2], A21[2][2], Ax[2];
    Ax[0] = Frag2{}; Ax[1] = Frag2{};
    #pragma unroll
    for (int rt = 0; rt < 2; ++rt) {
        int growt = (rt * 2 + (bl >> 3)) * H_ + lw * 8 + (bl & 7);
        #pragma unroll
        for (int kt = 0; kt < 2; ++kt) {
            int cb = v * 64 + kt * 32;         // wave v owns k in [64v, 64v+64)
            A10[rt][kt] = gatherA(Whh0, H_, growt, cb, H_, kq);
            A11[rt][kt] = gatherA(Wih1, H_, growt, cb, H_, kq);
            A21[rt][kt] = gatherA(Whh1, H_, growt, cb, H_, kq);
        }
        if (v < 2) Ax[rt] = gatherA(Wih0, F_, growt, v * 32, F_, kq);
    }

    __syncthreads();                  // init stores drained before flag
    if (tid == 0) astore_u32(&flags[w * FLGSTRIDE], 1u);

    for (int s = 0; s <= T_; ++s) {
        const bool do0 = (s < T_), do1 = (s > 0);
        unsigned* h1p = h1r[(s + 1) & 1];
        unsigned* h1c = h1r[s & 1];
        unsigned* h2p = h2r[s & 1];
        unsigned* h2c = h2r[(s + 1) & 1];

        f32x4 acc0[2] = {{0,0,0,0},{0,0,0,0}};
        f32x4 acc1[2] = {{0,0,0,0},{0,0,0,0}};

        // ---- x prefetch (pre-poll, pinned; poll's first vm_wait0 drains it) ----
        float4 xq0 = {0,0,0,0}, xq1 = {0,0,0,0};
        if (do0 && v < 2) {
            const float* p = x + ((size_t)(g * GB + bl) * T_ + s) * F_ + v * 32 + kq * 8;
            if (v == 0) { xq0 = cload4(p); xq1 = cload4(p + 4); }
            else if (kq == 0) xq0 = cload4(p);   // cols 32..35
        }

        // ---- group-local poll (64 flags, 1 dword/lane), 2-deep pipelined:
        //      two flag loads in flight; vmcnt(1) waits the older -> detect
        //      quantization ~RTT/2 instead of RTT. Never copy an in-flight
        //      asm-load register (SSA alternation pa/pb).
        {
            const unsigned* fp = flags + (g * GW + lane) * FLGSTRIDE;
            const unsigned tgt = (unsigned)(s + 1);
            unsigned pa = llc_load1(fp);
            vm_wait0();                           // drains x prefetch + pa
            if (!__all((int)(pa >= tgt))) {
                pa = llc_load1(fp);
                unsigned pb = llc_load1(fp);
                for (;;) {
                    vm_wait1();                   // pa (older) complete
                    if (__all((int)(pa >= tgt))) break;
                    pa = llc_load1(fp);
                    vm_wait1();                   // pb complete
                    if (__all((int)(pb >= tgt))) break;
                    pb = llc_load1(fp);
                }
                vm_wait0();                       // retire the younger in-flight load
            }
        }

        // ---- issue 8 LLC loads (h1 then h2), x-MFMA under their latency ----
        uint4 rA[4], rB[4];
        #pragma unroll
        for (int kt = 0; kt < 2; ++kt) {
            const unsigned* p = h1p + bl * H_ + v * 64 + kt * 32 + kq * 8;
            rA[kt*2] = llc_load4(p); rA[kt*2+1] = llc_load4(p + 4);
        }
        #pragma unroll
        for (int kt = 0; kt < 2; ++kt) {
            const unsigned* p = h2p + bl * H_ + v * 64 + kt * 32 + kq * 8;
            rB[kt*2] = llc_load4(p); rB[kt*2+1] = llc_load4(p + 4);
        }

        if (do0 && v < 2) {
            float xv[8] = { xq0.x, xq0.y, xq0.z, xq0.w, xq1.x, xq1.y, xq1.z, xq1.w };
            Frag2 xb = split8(xv);
            #pragma unroll
            for (int rt = 0; rt < 2; ++rt)
                acc0[rt] = mfma3(Ax[rt], xb, acc0[rt]);
        }

        vm_wait4();                               // h1 (4 oldest) ready
        #pragma unroll
        for (int kt = 0; kt < 2; ++kt) {
            Frag2 hb = fromPacked(rA[kt*2], rA[kt*2+1]);   // shared by both layers
            #pragma unroll
            for (int rt = 0; rt < 2; ++rt) {
                if (do0) acc0[rt] = mfma3(A10[rt][kt], hb, acc0[rt]);
                if (do1) acc1[rt] = mfma3(A11[rt][kt], hb, acc1[rt]);
            }
        }
        vm_wait0();                               // h2 ready
        if (do1) {
            #pragma unroll
            for (int kt = 0; kt < 2; ++kt) {
                Frag2 hb = fromPacked(rB[kt*2], rB[kt*2+1]);
                #pragma unroll
                for (int rt = 0; rt < 2; ++rt)
                    acc1[rt] = mfma3(A21[rt][kt], hb, acc1[rt]);
            }
        }

        // ---- cross-wave reduction staging ----
        #pragma unroll
        for (int rt = 0; rt < 2; ++rt)
            #pragma unroll
            for (int rg = 0; rg < 4; ++rg) {
                parts[v][0][rt][rg][lane] = acc0[rt][rg];
                parts[v][1][rt][rg][lane] = acc1[rt][rg];
            }
        __syncthreads();

        // ---- B: gates + cell; h into LDS staging. D(r,c): r = gate*8+u,
        //      rt = gate>>1, lane = ((gate&1)*2 + (u>>2))*16 + b, reg = u&3.
        if (tid < 256) {
            int layer = tid >> 7, u = (tid >> 4) & 7, b = tid & 15;
            bool actL = layer ? do1 : do0;
            if (actL) {
                float pre[4];
                #pragma unroll
                for (int gate = 0; gate < 4; ++gate) {
                    int rt = gate >> 1;
                    int ln = ((gate & 1) * 2 + (u >> 2)) * 16 + b;
                    int rg = u & 3;
                    float sum = bias[layer][gate][u];
                    #pragma unroll
                    for (int wv = 0; wv < NW; ++wv)
                        sum += parts[wv][layer][rt][rg][ln];
                    pre[gate] = sum;
                }
                float ig = sigm(pre[0]), ff = sigm(pre[1]);
                float gv = tanhf_(pre[2]), og = sigm(pre[3]);
                float cc = fmaf(ff, cs[layer][u][b], ig * gv);
                cs[layer][u][b] = cc;
                hstage[layer][u][b] = packhl(og * tanhf_(cc));
            }
        }
        __syncthreads();

        // ---- coalesced h writeback (wave 0 only) + flag. The final barrier is
        //      REMOVED: flag needs only wave-0's own stores drained (vm_wait0),
        //      and tid0 is in wave 0. Waves 1-7 flow into the next poll, which
        //      gates them on the whole group anyway.
        if (tid < 64) {
            int layer = tid >> 5, j = (tid >> 4) & 1, b = tid & 15;
            bool actL = layer ? do1 : do0;
            if (actL) {
                u32x4 q = { hstage[layer][j*4+0][b], hstage[layer][j*4+1][b],
                            hstage[layer][j*4+2][b], hstage[layer][j*4+3][b] };
                gstore4((layer ? h2c : h1c) + b * H_ + lw * 8 + j * 4, q);
            }
            vm_wait0();                            // wave-0 stores at LLC
        }
        if (tid == 0) astore_u32(&flags[w * FLGSTRIDE], (unsigned)(s + 2));
    }

    // ---- group-local projection: WGs lw 0,1 compute out[g*16+b][lw*32 + 0..31] ----
    if (lw < 2) {
        const unsigned* fp = flags + (g * GW + lane) * FLGSTRIDE;
        for (;;) {
            unsigned a = llc_load1(fp);
            vm_wait0();
            if (__all((int)(a >= (unsigned)(T_ + 2)))) break;
        }
        const unsigned* h2l = h2r[(T_ + 1) & 1];   // h2[T-1]
        int b = tid >> 5, c = lw * 32 + (tid & 31);
        const float* wrow = Wout + (size_t)c * H_;
        float a = 0.0f;
        for (int blk2 = 0; blk2 < 8; ++blk2) {
            uint4 q[16];
            #pragma unroll
            for (int i = 0; i < 16; ++i)
                q[i] = llc_load4(h2l + b * H_ + blk2 * 64 + i * 4);
            vm_wait0();
            #pragma unroll
            for (int i = 0; i < 16; ++i) {
                unsigned pv[4] = { q[i].x, q[i].y, q[i].z, q[i].w };
                #pragma unroll
                for (int e = 0; e < 4; ++e) {
                    float hv = __uint_as_float(pv[e] << 16) + __uint_as_float(pv[e] & 0xFFFF0000u);
                    a = fmaf(hv, wrow[blk2 * 64 + i * 4 + e], a);
                }
            }
        }
        out[(g * GB + b) * C_ + c] = a + bout[c];
    }
}

extern "C" void kernel_launch(void* const* d_in, const int* in_sizes, int n_in,
                              void* d_out, int out_size, void* d_ws, size_t ws_size,
                              hipStream_t stream)
{
    const float* x    = (const float*)d_in[0];
    const float* Wih0 = (const float*)d_in[1];
    const float* Whh0 = (const float*)d_in[2];
    const float* bih0 = (const float*)d_in[3];
    const float* bhh0 = (const float*)d_in[4];
    const float* Wih1 = (const float*)d_in[5];
    const float* Whh1 = (const float*)d_in[6];
    const float* bih1 = (const float*)d_in[7];
    const float* bhh1 = (const float*)d_in[8];
    const float* Wout = (const float*)d_in[9];
    const float* bout = (const float*)d_in[10];
    float* out = (float*)d_out;
    unsigned* wsu = (unsigned*)d_ws;

    // reset padded epoch flags (in-graph, deterministic across replays)
    (void)hipMemsetAsync(d_ws, 0, FLGN_U32 * sizeof(unsigned), stream);

    void* args[] = { (void*)&x, (void*)&Wih0, (void*)&Whh0, (void*)&bih0, (void*)&bhh0,
                     (void*)&Wih1, (void*)&Whh1, (void*)&bih1, (void*)&bhh1,
                     (void*)&Wout, (void*)&bout, (void*)&out, (void*)&wsu };
    (void)hipLaunchCooperativeKernel((void*)lstm_all, dim3(NWG), dim3(BLK), args, 0, stream);
}

// Round 17
// 7224.523 us; speedup vs baseline: 1.4829x; 1.4829x over previous
//
#include <hip/hip_runtime.h>

constexpr int F_ = 36;
constexpr int H_ = 512;
constexpr int T_ = 1500;
constexpr int C_ = 64;
constexpr int NWG = 256;
constexpr int BLK = 512;
constexpr int NW = 8;
constexpr int NGRP = 4;            // independent batch groups (16 batch each)
constexpr int GW = 64;             // WGs per group
constexpr int GB = 16;             // batch elements per group
constexpr int GRING = GB * H_;     // 8192 u32 per ring buffer
constexpr int FLGSTRIDE = 32;      // one flag per 128B line
constexpr unsigned FLGN_U32 = NWG * FLGSTRIDE;   // 8192 u32 = 32KB

#define SCOPE_AGENT __HIP_MEMORY_SCOPE_AGENT

typedef __attribute__((ext_vector_type(8))) short bf16x8;
typedef __attribute__((ext_vector_type(4))) float f32x4;
typedef __attribute__((ext_vector_type(4))) unsigned u32x4;

// ---- cross-XCD primitives (R5/R6/R11/R15-proven): sc0sc1 write-through + LLC loads ----
__device__ __forceinline__ void astore_u32(unsigned* p, unsigned v) {
    __hip_atomic_store(p, v, __ATOMIC_RELAXED, SCOPE_AGENT);
}
__device__ __forceinline__ uint4 llc_load4(const unsigned* p) {
    uint4 r;
    asm volatile("global_load_dwordx4 %0, %1, off sc0 sc1" : "=v"(r) : "v"(p));
    return r;
}
__device__ __forceinline__ unsigned llc_load1(const unsigned* p) {
    unsigned r;
    asm volatile("global_load_dword %0, %1, off sc0 sc1" : "=v"(r) : "v"(p));
    return r;
}
// plain cached load, position-pinned (immutable x prefetch)
__device__ __forceinline__ float4 cload4(const float* p) {
    float4 r;
    asm volatile("global_load_dwordx4 %0, %1, off" : "=v"(r) : "v"(p));
    return r;
}
__device__ __forceinline__ void gstore4(unsigned* p, u32x4 v) {
    asm volatile("global_store_dwordx4 %0, %1, off sc0 sc1" :: "v"(p), "v"(v) : "memory");
}
// rule #18: sched_barrier(0) after inline-asm waitcnt
__device__ __forceinline__ void vm_wait0() { asm volatile("s_waitcnt vmcnt(0)" ::: "memory"); __builtin_amdgcn_sched_barrier(0); }
__device__ __forceinline__ void vm_wait4() { asm volatile("s_waitcnt vmcnt(4)" ::: "memory"); __builtin_amdgcn_sched_barrier(0); }

__device__ __forceinline__ float sigm(float x) { return 1.0f / (1.0f + __expf(-x)); }
__device__ __forceinline__ float tanhf_(float x) { return 1.0f - 2.0f / (__expf(2.0f * x) + 1.0f); }

// ---- bf16 hi/lo split machinery (R6-proven) ----
__device__ __forceinline__ unsigned bf16rne(float f) {
    unsigned u = __float_as_uint(f);
    return (u + 0x7FFFu + ((u >> 16) & 1u)) >> 16;
}
__device__ __forceinline__ unsigned packhl(float h) {
    unsigned hi = bf16rne(h);
    float lo = h - __uint_as_float(hi << 16);
    return hi | (bf16rne(lo) << 16);
}

struct Frag2 { bf16x8 hi, lo; };

__device__ __forceinline__ Frag2 split8(const float v[8]) {
    union { unsigned u[4]; bf16x8 x; } hi, lo;
    #pragma unroll
    for (int j = 0; j < 4; ++j) {
        unsigned a = bf16rne(v[2*j]), b = bf16rne(v[2*j+1]);
        float ra = v[2*j]   - __uint_as_float(a << 16);
        float rb = v[2*j+1] - __uint_as_float(b << 16);
        hi.u[j] = a | (b << 16);
        lo.u[j] = bf16rne(ra) | (bf16rne(rb) << 16);
    }
    return { hi.x, lo.x };
}
__device__ __forceinline__ Frag2 fromPacked(const uint4& q0, const uint4& q1) {
    unsigned p[8] = { q0.x, q0.y, q0.z, q0.w, q1.x, q1.y, q1.z, q1.w };
    union { unsigned u[4]; bf16x8 x; } hi, lo;
    #pragma unroll
    for (int j = 0; j < 4; ++j) {
        hi.u[j] = (p[2*j] & 0xFFFFu) | (p[2*j+1] << 16);
        lo.u[j] = (p[2*j] >> 16) | (p[2*j+1] & 0xFFFF0000u);
    }
    return { hi.x, lo.x };
}
__device__ __forceinline__ f32x4 mfma3(const Frag2& a, const Frag2& b, f32x4 c) {
    c = __builtin_amdgcn_mfma_f32_16x16x32_bf16(a.hi, b.hi, c, 0, 0, 0);
    c = __builtin_amdgcn_mfma_f32_16x16x32_bf16(a.hi, b.lo, c, 0, 0, 0);
    c = __builtin_amdgcn_mfma_f32_16x16x32_bf16(a.lo, b.hi, c, 0, 0, 0);
    return c;
}
__device__ Frag2 gatherA(const float* W, int rstride, int grow, int colbase, int ncols, int kq) {
    float v[8];
    #pragma unroll
    for (int e = 0; e < 8; ++e) {
        int col = colbase + kq * 8 + e;
        v[e] = (col < ncols) ? W[(size_t)grow * rstride + col] : 0.0f;
    }
    return split8(v);
}

__global__ void __launch_bounds__(BLK, 2) lstm_all(
    const float* __restrict__ x,
    const float* __restrict__ Wih0, const float* __restrict__ Whh0,
    const float* __restrict__ bih0, const float* __restrict__ bhh0,
    const float* __restrict__ Wih1, const float* __restrict__ Whh1,
    const float* __restrict__ bih1, const float* __restrict__ bhh1,
    const float* __restrict__ Wout, const float* __restrict__ bout,
    float* __restrict__ out, unsigned* __restrict__ wsu)
{
    const int w = blockIdx.x, tid = threadIdx.x;
    const int v = tid >> 6, lane = tid & 63;
    const int bl = lane & 15;        // B-frag col = group-local batch / A-row within tile
    const int kq = lane >> 4;        // k-quarter within frag
    const int g = w >> 6, lw = w & 63;   // group, WG-in-group

    __shared__ float parts[NW][2][2][4][65];   // [wave][layer][row-tile][reg][lane(+pad)]
    __shared__ float cs[2][8][GB];             // cell state [layer][unit][b]
    __shared__ float bias[2][4][8];            // [layer][gate][unit]
    __shared__ unsigned hstage[2][8][GB];      // packed h staging [layer][unit][b]

    unsigned* flags = wsu;                     // flag[w] at w*FLGSTRIDE (line-padded)
    unsigned* greg = wsu + FLGN_U32 + (size_t)g * 4 * GRING;   // group ring region
    unsigned* h1r[2] = { greg, greg + GRING };
    unsigned* h2r[2] = { greg + 2 * GRING, greg + 3 * GRING };

    // ---- init: zero this group's rings (exactly one u32 per thread), cs, bias ----
    astore_u32(greg + lw * BLK + tid, 0u);     // 64 WGs x 512 = 32768 = 4*GRING
    if (tid < 256) ((float*)cs)[tid] = 0.0f;   // 2*8*16 = 256
    if (tid < 64) {
        int layer = tid >> 5, gate = (tid >> 3) & 3, u = tid & 7;
        int grow = gate * H_ + lw * 8 + u;
        bias[layer][gate][u] = layer ? (bih1[grow] + bhh1[grow]) : (bih0[grow] + bhh0[grow]);
    }

    // ---- A-fragments in VGPRs. Row mapping per layer: r = gate*8 + u (0..31),
    //      row-tile rt = r>>4; within tile, lane bl: gate = rt*2+(bl>>3), u = bl&7.
    Frag2 A10[2][2], A11[2][2], A21[2][2], Ax[2];
    Ax[0] = Frag2{}; Ax[1] = Frag2{};
    #pragma unroll
    for (int rt = 0; rt < 2; ++rt) {
        int growt = (rt * 2 + (bl >> 3)) * H_ + lw * 8 + (bl & 7);
        #pragma unroll
        for (int kt = 0; kt < 2; ++kt) {
            int cb = v * 64 + kt * 32;         // wave v owns k in [64v, 64v+64)
            A10[rt][kt] = gatherA(Whh0, H_, growt, cb, H_, kq);
            A11[rt][kt] = gatherA(Wih1, H_, growt, cb, H_, kq);
            A21[rt][kt] = gatherA(Whh1, H_, growt, cb, H_, kq);
        }
        if (v < 2) Ax[rt] = gatherA(Wih0, F_, growt, v * 32, F_, kq);
    }

    __syncthreads();                  // init stores drained before flag
    if (tid == 0) astore_u32(&flags[w * FLGSTRIDE], 1u);

    for (int s = 0; s <= T_; ++s) {
        const bool do0 = (s < T_), do1 = (s > 0);
        unsigned* h1p = h1r[(s + 1) & 1];
        unsigned* h1c = h1r[s & 1];
        unsigned* h2p = h2r[s & 1];
        unsigned* h2c = h2r[(s + 1) & 1];

        f32x4 acc0[2] = {{0,0,0,0},{0,0,0,0}};
        f32x4 acc1[2] = {{0,0,0,0},{0,0,0,0}};

        // ---- x prefetch (pre-poll, pinned; poll's vm_wait0 drains it) ----
        float4 xq0 = {0,0,0,0}, xq1 = {0,0,0,0};
        if (do0 && v < 2) {
            const float* p = x + ((size_t)(g * GB + bl) * T_ + s) * F_ + v * 32 + kq * 8;
            if (v == 0) { xq0 = cload4(p); xq1 = cload4(p + 4); }
            else if (kq == 0) xq0 = cload4(p);   // cols 32..35
        }

        // ---- group-local poll: 64 flags, ONE dword per lane ----
        {
            const unsigned* fp = flags + (g * GW + lane) * FLGSTRIDE;
            const unsigned tgt = (unsigned)(s + 1);
            for (;;) {
                unsigned a = llc_load1(fp);
                vm_wait0();
                if (__all((int)(a >= tgt))) break;
            }
        }

        // ---- issue 8 LLC loads (h1 then h2), x-MFMA under their latency ----
        uint4 rA[4], rB[4];
        #pragma unroll
        for (int kt = 0; kt < 2; ++kt) {
            const unsigned* p = h1p + bl * H_ + v * 64 + kt * 32 + kq * 8;
            rA[kt*2] = llc_load4(p); rA[kt*2+1] = llc_load4(p + 4);
        }
        #pragma unroll
        for (int kt = 0; kt < 2; ++kt) {
            const unsigned* p = h2p + bl * H_ + v * 64 + kt * 32 + kq * 8;
            rB[kt*2] = llc_load4(p); rB[kt*2+1] = llc_load4(p + 4);
        }

        if (do0 && v < 2) {
            float xv[8] = { xq0.x, xq0.y, xq0.z, xq0.w, xq1.x, xq1.y, xq1.z, xq1.w };
            Frag2 xb = split8(xv);
            #pragma unroll
            for (int rt = 0; rt < 2; ++rt)
                acc0[rt] = mfma3(Ax[rt], xb, acc0[rt]);
        }

        vm_wait4();                               // h1 (4 oldest) ready
        #pragma unroll
        for (int kt = 0; kt < 2; ++kt) {
            Frag2 hb = fromPacked(rA[kt*2], rA[kt*2+1]);   // shared by both layers
            #pragma unroll
            for (int rt = 0; rt < 2; ++rt) {
                if (do0) acc0[rt] = mfma3(A10[rt][kt], hb, acc0[rt]);
                if (do1) acc1[rt] = mfma3(A11[rt][kt], hb, acc1[rt]);
            }
        }
        vm_wait0();                               // h2 ready
        if (do1) {
            #pragma unroll
            for (int kt = 0; kt < 2; ++kt) {
                Frag2 hb = fromPacked(rB[kt*2], rB[kt*2+1]);
                #pragma unroll
                for (int rt = 0; rt < 2; ++rt)
                    acc1[rt] = mfma3(A21[rt][kt], hb, acc1[rt]);
            }
        }

        // ---- cross-wave reduction staging ----
        #pragma unroll
        for (int rt = 0; rt < 2; ++rt)
            #pragma unroll
            for (int rg = 0; rg < 4; ++rg) {
                parts[v][0][rt][rg][lane] = acc0[rt][rg];
                parts[v][1][rt][rg][lane] = acc1[rt][rg];
            }
        __syncthreads();

        // ---- B: gates + cell; h into LDS staging. D(r,c): r = gate*8+u,
        //      rt = gate>>1, lane = ((gate&1)*2 + (u>>2))*16 + b, reg = u&3.
        if (tid < 256) {
            int layer = tid >> 7, u = (tid >> 4) & 7, b = tid & 15;
            bool actL = layer ? do1 : do0;
            if (actL) {
                float pre[4];
                #pragma unroll
                for (int gate = 0; gate < 4; ++gate) {
                    int rt = gate >> 1;
                    int ln = ((gate & 1) * 2 + (u >> 2)) * 16 + b;
                    int rg = u & 3;
                    float sum = bias[layer][gate][u];
                    #pragma unroll
                    for (int wv = 0; wv < NW; ++wv)
                        sum += parts[wv][layer][rt][rg][ln];
                    pre[gate] = sum;
                }
                float ig = sigm(pre[0]), ff = sigm(pre[1]);
                float gv = tanhf_(pre[2]), og = sigm(pre[3]);
                float cc = fmaf(ff, cs[layer][u][b], ig * gv);
                cs[layer][u][b] = cc;
                hstage[layer][u][b] = packhl(og * tanhf_(cc));
            }
        }
        __syncthreads();

        // ---- coalesced h writeback: 16B sc0sc1 store per (layer, j, b); wave 0 only ----
        if (tid < 64) {
            int layer = tid >> 5, j = (tid >> 4) & 1, b = tid & 15;
            bool actL = layer ? do1 : do0;
            if (actL) {
                u32x4 q = { hstage[layer][j*4+0][b], hstage[layer][j*4+1][b],
                            hstage[layer][j*4+2][b], hstage[layer][j*4+3][b] };
                gstore4((layer ? h2c : h1c) + b * H_ + lw * 8 + j * 4, q);
            }
            vm_wait0();                            // asm stores drained at LLC
        }
        __syncthreads();
        if (tid == 0) astore_u32(&flags[w * FLGSTRIDE], (unsigned)(s + 2));
    }

    // ---- group-local projection: WGs lw 0,1 compute out[g*16+b][lw*32 + 0..31] ----
    if (lw < 2) {
        const unsigned* fp = flags + (g * GW + lane) * FLGSTRIDE;
        for (;;) {
            unsigned a = llc_load1(fp);
            vm_wait0();
            if (__all((int)(a >= (unsigned)(T_ + 2)))) break;
        }
        const unsigned* h2l = h2r[(T_ + 1) & 1];   // h2[T-1]
        int b = tid >> 5, c = lw * 32 + (tid & 31);
        const float* wrow = Wout + (size_t)c * H_;
        float a = 0.0f;
        for (int blk2 = 0; blk2 < 8; ++blk2) {
            uint4 q[16];
            #pragma unroll
            for (int i = 0; i < 16; ++i)
                q[i] = llc_load4(h2l + b * H_ + blk2 * 64 + i * 4);
            vm_wait0();
            #pragma unroll
            for (int i = 0; i < 16; ++i) {
                unsigned pv[4] = { q[i].x, q[i].y, q[i].z, q[i].w };
                #pragma unroll
                for (int e = 0; e < 4; ++e) {
                    float hv = __uint_as_float(pv[e] << 16) + __uint_as_float(pv[e] & 0xFFFF0000u);
                    a = fmaf(hv, wrow[blk2 * 64 + i * 4 + e], a);
                }
            }
        }
        out[(g * GB + b) * C_ + c] = a + bout[c];
    }
}

extern "C" void kernel_launch(void* const* d_in, const int* in_sizes, int n_in,
                              void* d_out, int out_size, void* d_ws, size_t ws_size,
                              hipStream_t stream)
{
    const float* x    = (const float*)d_in[0];
    const float* Wih0 = (const float*)d_in[1];
    const float* Whh0 = (const float*)d_in[2];
    const float* bih0 = (const float*)d_in[3];
    const float* bhh0 = (const float*)d_in[4];
    const float* Wih1 = (const float*)d_in[5];
    const float* Whh1 = (const float*)d_in[6];
    const float* bih1 = (const float*)d_in[7];
    const float* bhh1 = (const float*)d_in[8];
    const float* Wout = (const float*)d_in[9];
    const float* bout = (const float*)d_in[10];
    float* out = (float*)d_out;
    unsigned* wsu = (unsigned*)d_ws;

    // reset padded epoch flags (in-graph, deterministic across replays)
    (void)hipMemsetAsync(d_ws, 0, FLGN_U32 * sizeof(unsigned), stream);

    void* args[] = { (void*)&x, (void*)&Wih0, (void*)&Whh0, (void*)&bih0, (void*)&bhh0,
                     (void*)&Wih1, (void*)&Whh1, (void*)&bih1, (void*)&bhh1,
                     (void*)&Wout, (void*)&bout, (void*)&out, (void*)&wsu };
    (void)hipLaunchCooperativeKernel((void*)lstm_all, dim3(NWG), dim3(BLK), args, 0, stream);
}